// Round 11
// baseline (16195.840 us; speedup 1.0000x reference)
//
#include <hip/hip_runtime.h>
#include <stdint.h>

// RNNLayer: h_t = tanh([x_t, h_{t-1}] @ W + b), outputs all h_t [B,T,H] fp32.
// B=64, T=1024, D=1024, H=1024.  W: [D+H, H] fp32.
//
// Phase 1: XP = x @ W[:D] + b -> d_out (bf16 MFMA, 128x128 tiles).
// Phase 2: persistent scan, 64 WGs = 4 rings x 16 col-groups, 512 thr =
//   4 COMPUTE waves (16 cols each, Wh in 128 VGPRs) + 4 POLL waves.
//   Round-11 = round-10 structure with two fixes:
//   (1) Poll loads are plain __hip_atomic_load (relaxed/agent, r5/r9-proven).
//       Round 10's inline-asm ping-pong broke: after `break`, the other
//       batch's in-flight loads targeted registers the compiler considered
//       DEAD and reallocated -> loads landed into live values. Compiler-
//       generated loads are tracked by the waitcnt pass (counted vmcnt,
//       no reuse while pending) -> pipelined polling safe by construction.
//   (2) Compute waves use raw s_barrier (no vmcnt drain on the barrier
//       path; __syncthreads put the sc1 store-ack RTT on the critical path
//       every step). Same-slot store ordering (t vs t+2) preserved by a
//       vmcnt(0) at the TOP of each iteration (drains step t-1 stores,
//       aged one full step -> free).
//   Exchange: u32 = {tag:16 | bf16:16}, self-validating, agent-scope sc1.

#define T_LEN 1024
#define HID   1024

typedef float  f32x4  __attribute__((ext_vector_type(4)));
typedef __bf16 bf16x8 __attribute__((ext_vector_type(8)));
typedef unsigned long long u64;

// ---------------- Phase 1: x_proj GEMM (unchanged) ----------------
__global__ __launch_bounds__(256) void xproj_gemm(
    const float* __restrict__ x, const float* __restrict__ W,
    const float* __restrict__ bias, float* __restrict__ out)
{
    __shared__ __align__(16) __bf16 As[128][40];
    __shared__ __align__(16) __bf16 Bs[128][40];

    const int bid = blockIdx.x;
    const int n0  = (bid & 7) << 7;
    const int64_t r0 = (int64_t)(bid >> 3) << 7;
    const int tid  = threadIdx.x;
    const int lane = tid & 63;
    const int w    = tid >> 6;
    const int hi   = lane >> 4, lo = lane & 15;
    const int wm   = (w >> 1) << 6, wn = (w & 1) << 6;

    f32x4 acc[4][4] = {};

    const int arow = tid >> 1, akh = (tid & 1) << 4;
    const int bk   = tid >> 3, bnh = (tid & 7) << 4;

    for (int k0 = 0; k0 < 1024; k0 += 32) {
        {
            const float* src = x + (r0 + arow) * 1024 + k0 + akh;
            bf16x8 t0, t1;
            #pragma unroll
            for (int i2 = 0; i2 < 8; ++i2) { t0[i2] = (__bf16)src[i2]; t1[i2] = (__bf16)src[8 + i2]; }
            *(bf16x8*)&As[arow][akh]     = t0;
            *(bf16x8*)&As[arow][akh + 8] = t1;
        }
        {
            const float* src = W + (int64_t)(k0 + bk) * 1024 + n0 + bnh;
            #pragma unroll
            for (int i2 = 0; i2 < 16; ++i2) {
                int col = bnh + i2;
                Bs[col][bk ^ (((col >> 4) & 3) << 3)] = (__bf16)src[i2];
            }
        }
        __syncthreads();

        bf16x8 af[4], bfr[4];
        #pragma unroll
        for (int f = 0; f < 4; ++f)
            af[f] = *(const bf16x8*)&As[wm + f * 16 + lo][hi << 3];
        #pragma unroll
        for (int f = 0; f < 4; ++f) {
            const int cswz = (((wn >> 4) + f) & 3) << 3;
            bfr[f] = *(const bf16x8*)&Bs[wn + f * 16 + lo][(hi << 3) ^ cswz];
        }
        #pragma unroll
        for (int fm = 0; fm < 4; ++fm)
            #pragma unroll
            for (int fn = 0; fn < 4; ++fn)
                acc[fm][fn] = __builtin_amdgcn_mfma_f32_16x16x32_bf16(af[fm], bfr[fn], acc[fm][fn], 0, 0, 0);
        __syncthreads();
    }

    #pragma unroll
    for (int fm = 0; fm < 4; ++fm) {
        const int64_t mrow = r0 + wm + fm * 16 + hi * 4;
        #pragma unroll
        for (int fn = 0; fn < 4; ++fn) {
            const int col = n0 + wn + fn * 16 + lo;
            const float bv = bias[col];
            #pragma unroll
            for (int r = 0; r < 4; ++r)
                out[(mrow + r) * 1024 + col] = acc[fm][fn][r] + bv;
        }
    }
}

// fast tanh: 1 - 2/(exp(2x)+1); saturates correctly for |x| large.
__device__ __forceinline__ float tanh_fast(float x) {
    float e = __builtin_amdgcn_exp2f(x * 2.885390082f);
    return 1.0f - 2.0f * __builtin_amdgcn_rcpf(e + 1.0f);
}

#define FB(x_) __builtin_bit_cast(float, (x_))

// load one 32-u64 batch (compiler-generated, waitcnt-tracked)
#define LOADB(q_) do {                                                              \
    _Pragma("unroll")                                                               \
    for (int j = 0; j < 32; ++j)                                                    \
        q_[j] = __hip_atomic_load(bp + j, __ATOMIC_RELAXED, __HIP_MEMORY_SCOPE_AGENT); \
} while (0)

// wave-uniform tag validation
#define TAGOK(q_, ok_) do {                                                         \
    unsigned bad_ = 0;                                                              \
    _Pragma("unroll")                                                               \
    for (int j = 0; j < 32; ++j) {                                                  \
        bad_ |= ((unsigned)(q_[j] >> 16) & 0xffffu) ^ et;                           \
        bad_ |= ((unsigned)(q_[j] >> 48)) ^ et;                                     \
    }                                                                               \
    ok_ = __all(bad_ == 0);                                                         \
} while (0)

// unpack {tag|bf16}x2 u64s -> packed bf16x2 dwords -> swizzled b128 LDS writes
#define STAGE32(q_) do {                                                            \
    unsigned dwp_[32];                                                              \
    _Pragma("unroll")                                                               \
    for (int j = 0; j < 32; ++j)                                                    \
        dwp_[j] = __builtin_amdgcn_perm((unsigned)(q_[j] >> 32), (unsigned)q_[j],   \
                                        0x05040100u);                               \
    unsigned char* w0_ = Ab + (2 * kk_) * 1024;                                     \
    unsigned char* w1_ = w0_ + 1024;                                                \
    _Pragma("unroll")                                                               \
    for (int i = 0; i < 4; ++i) {                                                   \
        *(f32x4*)(w0_ + ((((unsigned)(i * 16 + srow_)) ^ fsw_) << 4)) =             \
            (f32x4){FB(dwp_[4*i]), FB(dwp_[4*i+1]), FB(dwp_[4*i+2]), FB(dwp_[4*i+3])}; \
        *(f32x4*)(w1_ + ((((unsigned)(i * 16 + srow_)) ^ fsw_) << 4)) =             \
            (f32x4){FB(dwp_[16+4*i]), FB(dwp_[16+4*i+1]), FB(dwp_[16+4*i+2]), FB(dwp_[16+4*i+3])}; \
    }                                                                               \
} while (0)

// ---------------- Phase 2: persistent recurrent scan ----------------
// 64 WGs = 4 rings (16 rows) x 16 col-groups (64 cols). 512 threads:
// waves 0-3 compute (16 cols each), waves 4-7 poll+stage.
__global__ __launch_bounds__(512, 2) void rnn_scan(
    const float* __restrict__ W, float* __restrict__ out, unsigned int* hx)
{
    __shared__ __align__(16) unsigned char A_lds[2][32 * 1024];  // dbuf 2x32KB

    const int bid = blockIdx.x;
    const int ig  = bid >> 4;        // ring: batch rows 16*ig..+15
    const int jg  = bid & 15;        // col group: hidden cols 64*jg..+63
    const int tid = threadIdx.x;
    const int lane = tid & 63;
    const int wv  = tid >> 6;
    const int hi  = lane >> 4, lo = lane & 15;

    if (wv < 4) {
        // ================= COMPUTE waves =================
        const int col = jg * 64 + wv * 16 + lo;
        bf16x8 breg[32];
        {
            const float* wb = W + (int64_t)1024 * 1024 + col;   // Wh rows start at 1024
            #pragma unroll
            for (int kb = 0; kb < 32; ++kb) {
                const float* src = wb + (int64_t)(kb * 32 + hi * 8) * 1024;
                bf16x8 tf;
                #pragma unroll
                for (int j = 0; j < 8; ++j) tf[j] = (__bf16)src[(int64_t)j * 1024];
                breg[kb] = tf;
            }
        }
        const int64_t rstride = (int64_t)T_LEN * HID;
        float* pr0 = out + (int64_t)(ig * 16 + hi * 4) * rstride + col;
        const int wr0 = (ig * 16 + hi * 4) * 1024 + col;

        // ---- t = 0 ----
        float xc0 = pr0[0], xc1 = pr0[rstride], xc2 = pr0[2 * rstride], xc3 = pr0[3 * rstride];
        float h0 = tanh_fast(xc0), h1 = tanh_fast(xc1), h2 = tanh_fast(xc2), h3 = tanh_fast(xc3);
        {
            const unsigned tw = 1u << 16;                 // tag 1 -> slot 0
            unsigned* q_ = hx + wr0;
            __hip_atomic_store(q_,        tw | __builtin_bit_cast(unsigned short, (__bf16)h0), __ATOMIC_RELAXED, __HIP_MEMORY_SCOPE_AGENT);
            __hip_atomic_store(q_ + 1024, tw | __builtin_bit_cast(unsigned short, (__bf16)h1), __ATOMIC_RELAXED, __HIP_MEMORY_SCOPE_AGENT);
            __hip_atomic_store(q_ + 2048, tw | __builtin_bit_cast(unsigned short, (__bf16)h2), __ATOMIC_RELAXED, __HIP_MEMORY_SCOPE_AGENT);
            __hip_atomic_store(q_ + 3072, tw | __builtin_bit_cast(unsigned short, (__bf16)h3), __ATOMIC_RELAXED, __HIP_MEMORY_SCOPE_AGENT);
        }
        pr0[0] = h0; pr0[rstride] = h1; pr0[2 * rstride] = h2; pr0[3 * rstride] = h3;
        // prefetch xp(1) (latency hides under poll wait)
        xc0 = pr0[HID]; xc1 = pr0[rstride + HID]; xc2 = pr0[2 * rstride + HID]; xc3 = pr0[3 * rstride + HID];
        __builtin_amdgcn_s_barrier();                     // BAR_0

        for (int t = 1; t < T_LEN; ++t) {
            __builtin_amdgcn_s_barrier();                 // BAR_t: buf(t&1) staged
            // drain step t-1 stores (aged ~1 step -> free). Guarantees same-slot
            // ordering: stores of step t-1 complete before step t+1's are issued.
            asm volatile("s_waitcnt vmcnt(0)" ::: "memory");

            // prefetch xp(t+1) — consumed next iteration
            const int tn = (t + 1 < T_LEN) ? t + 1 : t;
            float p0 = pr0[(int64_t)tn * HID];
            float p1 = pr0[(int64_t)tn * HID + rstride];
            float p2 = pr0[(int64_t)tn * HID + 2 * rstride];
            float p3 = pr0[(int64_t)tn * HID + 3 * rstride];

            const unsigned char* Ab = &A_lds[t & 1][0];
            f32x4 a0 = {0.f,0.f,0.f,0.f}, a1 = a0, a2 = a0, a3 = a0;
            #pragma unroll
            for (int kb = 0; kb < 32; kb += 4) {
                bf16x8 x0 = *(const bf16x8*)(Ab + (kb + 0) * 1024 + (((unsigned)lane ^ (unsigned)(((kb + 0) >> 1) << 2)) << 4));
                bf16x8 x1 = *(const bf16x8*)(Ab + (kb + 1) * 1024 + (((unsigned)lane ^ (unsigned)(((kb + 1) >> 1) << 2)) << 4));
                bf16x8 x2 = *(const bf16x8*)(Ab + (kb + 2) * 1024 + (((unsigned)lane ^ (unsigned)(((kb + 2) >> 1) << 2)) << 4));
                bf16x8 x3 = *(const bf16x8*)(Ab + (kb + 3) * 1024 + (((unsigned)lane ^ (unsigned)(((kb + 3) >> 1) << 2)) << 4));
                a0 = __builtin_amdgcn_mfma_f32_16x16x32_bf16(x0, breg[kb + 0], a0, 0, 0, 0);
                a1 = __builtin_amdgcn_mfma_f32_16x16x32_bf16(x1, breg[kb + 1], a1, 0, 0, 0);
                a2 = __builtin_amdgcn_mfma_f32_16x16x32_bf16(x2, breg[kb + 2], a2, 0, 0, 0);
                a3 = __builtin_amdgcn_mfma_f32_16x16x32_bf16(x3, breg[kb + 3], a3, 0, 0, 0);
            }
            f32x4 acc = (a0 + a1) + (a2 + a3);

            h0 = tanh_fast(xc0 + acc[0]);
            h1 = tanh_fast(xc1 + acc[1]);
            h2 = tanh_fast(xc2 + acc[2]);
            h3 = tanh_fast(xc3 + acc[3]);

            // exchange stores first (fire-and-forget)
            const unsigned tw = (unsigned)(t + 1) << 16;
            unsigned* q_ = hx + (t & 1) * 65536 + wr0;
            __hip_atomic_store(q_,        tw | __builtin_bit_cast(unsigned short, (__bf16)h0), __ATOMIC_RELAXED, __HIP_MEMORY_SCOPE_AGENT);
            __hip_atomic_store(q_ + 1024, tw | __builtin_bit_cast(unsigned short, (__bf16)h1), __ATOMIC_RELAXED, __HIP_MEMORY_SCOPE_AGENT);
            __hip_atomic_store(q_ + 2048, tw | __builtin_bit_cast(unsigned short, (__bf16)h2), __ATOMIC_RELAXED, __HIP_MEMORY_SCOPE_AGENT);
            __hip_atomic_store(q_ + 3072, tw | __builtin_bit_cast(unsigned short, (__bf16)h3), __ATOMIC_RELAXED, __HIP_MEMORY_SCOPE_AGENT);

            pr0[(int64_t)t * HID]               = h0;     // fp32 outputs
            pr0[(int64_t)t * HID + rstride]     = h1;
            pr0[(int64_t)t * HID + 2 * rstride] = h2;
            pr0[(int64_t)t * HID + 3 * rstride] = h3;

            xc0 = p0; xc1 = p1; xc2 = p2; xc3 = p3;
        }
        asm volatile("s_waitcnt vmcnt(0)" ::: "memory");  // flush before endpgm
    } else {
        // ================= POLL waves =================
        const int ptid  = tid - 256;
        const int srow_ = ptid >> 4;                      // 0..15: slab row within ring
        const int kk_   = ptid & 15;                      // kb-pair: windows {2k, 2k+1}
        const unsigned fsw_ = (unsigned)(kk_ << 2);       // LDS swizzle f(kb) = (kb>>1)<<2
        const int chunk = ((ig * 16 + srow_) * 512) + kk_ * 32;   // u64 index

        __builtin_amdgcn_s_barrier();                     // BAR_0

        for (int t = 1; t < T_LEN; ++t) {
            const unsigned et = (unsigned)t;
            const u64* bp = (const u64*)(hx + ((t - 1) & 1) * 65536) + chunk;
            unsigned char* Ab = &A_lds[t & 1][0];

            u64 qa[32], qb[32];
            bool ok;
            LOADB(qa);
            for (;;) {
                LOADB(qb);                                // issue B before checking A
                __builtin_amdgcn_sched_barrier(0);        // pin issue-before-check
                TAGOK(qa, ok);
                if (ok) { STAGE32(qa); break; }
                LOADB(qa);                                // issue A before checking B
                __builtin_amdgcn_sched_barrier(0);
                TAGOK(qb, ok);
                if (ok) { STAGE32(qb); break; }
            }
            asm volatile("s_waitcnt lgkmcnt(0)" ::: "memory");   // ds_writes visible
            __builtin_amdgcn_s_barrier();                        // BAR_t
        }
        asm volatile("s_waitcnt vmcnt(0)" ::: "memory");
    }
}

extern "C" void kernel_launch(void* const* d_in, const int* in_sizes, int n_in,
                              void* d_out, int out_size, void* d_ws, size_t ws_size,
                              hipStream_t stream)
{
    const float* x    = (const float*)d_in[0];   // [64,1024,1024]
    const float* W    = (const float*)d_in[1];   // [2048,1024]
    const float* bias = (const float*)d_in[2];   // [1024]
    float* out = (float*)d_out;                  // [64,1024,1024]

    unsigned int* hx = (unsigned int*)d_ws;      // 2 slots x 64x1024 u32 = 512 KB

    (void)hipMemsetAsync(hx, 0, 524288, stream); // zero tags (expected tags >= 1)
    xproj_gemm<<<dim3(4096), dim3(256), 0, stream>>>(x, W, bias, out);
    rnn_scan<<<dim3(64), dim3(512), 0, stream>>>(W, out, hx);
}

// Round 12
// 7543.410 us; speedup vs baseline: 2.1470x; 2.1470x over previous
//
#include <hip/hip_runtime.h>
#include <stdint.h>

// RNNLayer: h_t = tanh([x_t, h_{t-1}] @ W + b), outputs all h_t [B,T,H] fp32.
// B=64, T=1024, D=1024, H=1024.  W: [D+H, H] fp32.
//
// Phase 1: XP = x @ W[:D] + b -> d_out (bf16 MFMA, 128x128 tiles).
// Phase 2: persistent scan, 32 scan WGs = 4 rings x 8 col-groups (512 thr,
//   16 rows x 128 cols, Wh register-resident) + 224 HEATER WGs.
//   Protocol = round 5's proven core: h exchanged as u32={tag:16|bf16:16}
//   via relaxed agent (sc1) atomics; per-thread direct tag spin (fire-and-
//   forget producer stores; WAR-safe with 2 slots: observing tag t from all
//   ring producers implies their step-(t-1) reads retired).
//   Round-12 thesis: step latency was protocol-invariant at ~7.5us across
//   traffic(16MB->32B), WGs(256->32), fan-in(64->8), flag/data spin => NOT
//   a protocol cost. At <1% utilization the DVFS governor idles the clock;
//   7.5us at ~500MHz == the ~1.5-2us critical path repeatedly predicted at
//   2.4GHz. Fix: keep the chip HOT. (a) spin loops run a live dependent-FMA
//   chain instead of s_sleep (also throttles poll flood); (b) heater WGs on
//   idle CUs run FMA chains until scan posts done (write nothing -> safe).
//   LDS = round 9's measured-zero-conflict layout [kb][slot^(kb&7)].

#define T_LEN 1024
#define HID   1024

typedef float  f32x4  __attribute__((ext_vector_type(4)));
typedef __bf16 bf16x8 __attribute__((ext_vector_type(8)));
typedef unsigned long long u64;

// ---------------- Phase 1: x_proj GEMM (unchanged) ----------------
__global__ __launch_bounds__(256) void xproj_gemm(
    const float* __restrict__ x, const float* __restrict__ W,
    const float* __restrict__ bias, float* __restrict__ out)
{
    __shared__ __align__(16) __bf16 As[128][40];
    __shared__ __align__(16) __bf16 Bs[128][40];

    const int bid = blockIdx.x;
    const int n0  = (bid & 7) << 7;
    const int64_t r0 = (int64_t)(bid >> 3) << 7;
    const int tid  = threadIdx.x;
    const int lane = tid & 63;
    const int w    = tid >> 6;
    const int hi   = lane >> 4, lo = lane & 15;
    const int wm   = (w >> 1) << 6, wn = (w & 1) << 6;

    f32x4 acc[4][4] = {};

    const int arow = tid >> 1, akh = (tid & 1) << 4;
    const int bk   = tid >> 3, bnh = (tid & 7) << 4;

    for (int k0 = 0; k0 < 1024; k0 += 32) {
        {
            const float* src = x + (r0 + arow) * 1024 + k0 + akh;
            bf16x8 t0, t1;
            #pragma unroll
            for (int i2 = 0; i2 < 8; ++i2) { t0[i2] = (__bf16)src[i2]; t1[i2] = (__bf16)src[8 + i2]; }
            *(bf16x8*)&As[arow][akh]     = t0;
            *(bf16x8*)&As[arow][akh + 8] = t1;
        }
        {
            const float* src = W + (int64_t)(k0 + bk) * 1024 + n0 + bnh;
            #pragma unroll
            for (int i2 = 0; i2 < 16; ++i2) {
                int col = bnh + i2;
                Bs[col][bk ^ (((col >> 4) & 3) << 3)] = (__bf16)src[i2];
            }
        }
        __syncthreads();

        bf16x8 af[4], bfr[4];
        #pragma unroll
        for (int f = 0; f < 4; ++f)
            af[f] = *(const bf16x8*)&As[wm + f * 16 + lo][hi << 3];
        #pragma unroll
        for (int f = 0; f < 4; ++f) {
            const int cswz = (((wn >> 4) + f) & 3) << 3;
            bfr[f] = *(const bf16x8*)&Bs[wn + f * 16 + lo][(hi << 3) ^ cswz];
        }
        #pragma unroll
        for (int fm = 0; fm < 4; ++fm)
            #pragma unroll
            for (int fn = 0; fn < 4; ++fn)
                acc[fm][fn] = __builtin_amdgcn_mfma_f32_16x16x32_bf16(af[fm], bfr[fn], acc[fm][fn], 0, 0, 0);
        __syncthreads();
    }

    #pragma unroll
    for (int fm = 0; fm < 4; ++fm) {
        const int64_t mrow = r0 + wm + fm * 16 + hi * 4;
        #pragma unroll
        for (int fn = 0; fn < 4; ++fn) {
            const int col = n0 + wn + fn * 16 + lo;
            const float bv = bias[col];
            #pragma unroll
            for (int r = 0; r < 4; ++r)
                out[(mrow + r) * 1024 + col] = acc[fm][fn][r] + bv;
        }
    }
}

// fast tanh: 1 - 2/(exp(2x)+1); saturates correctly for |x| large.
__device__ __forceinline__ float tanh_fast(float x) {
    float e = __builtin_amdgcn_exp2f(x * 2.885390082f);
    return 1.0f - 2.0f * __builtin_amdgcn_rcpf(e + 1.0f);
}

#define FB(x_) __builtin_bit_cast(float, (x_))

// ---------------- Phase 2: persistent recurrent scan + heaters ----------------
// Grid 256 x 512 thr. bid 0..31: scan (4 rings x 8 col-groups). bid 32..255: heaters.
__global__ __launch_bounds__(512, 2) void rnn_scan(
    const float* __restrict__ W, float* __restrict__ out,
    unsigned int* hx, int* done)
{
    __shared__ __align__(16) unsigned char A_lds[32 * 1024];   // [kb][slot^(kb&7)]

    const int bid = blockIdx.x;
    const int tid = threadIdx.x;
    const int wv  = tid >> 6;

    if (bid >= 32) {
        // ============== HEATER: keep DVFS up while the scan runs ==============
        if (wv != 0) return;                       // one wave per heater WG
        float f0 = 1.0f, f1 = 1.125f, f2 = 1.25f, f3 = 1.375f;
        for (;;) {
            #pragma unroll
            for (int i = 0; i < 256; ++i) {        // 1024 FMAs (~0.4us) per done-check
                f0 = __builtin_fmaf(f0, 1.0000001f, 1.0e-7f);
                f1 = __builtin_fmaf(f1, 0.9999999f, 1.1e-7f);
                f2 = __builtin_fmaf(f2, 1.0000002f, 1.2e-7f);
                f3 = __builtin_fmaf(f3, 0.9999998f, 1.3e-7f);
            }
            asm volatile("" :: "v"(f0), "v"(f1), "v"(f2), "v"(f3));   // keep live
            if (__hip_atomic_load(done, __ATOMIC_RELAXED, __HIP_MEMORY_SCOPE_AGENT) >= 32)
                return;
        }
    }

    // ============================== SCAN WGs ==============================
    const int ig  = bid >> 3;        // ring: batch rows 16*ig..+15
    const int jg  = bid & 7;         // col group: hidden cols 128*jg..+127
    const int lane = tid & 63;
    const int hi  = lane >> 4, lo = lane & 15;

    // one-time: Wh B-frags for this wave's 16 cols, ALL K, in registers
    const int col = jg * 128 + wv * 16 + lo;
    bf16x8 breg[32];
    {
        const float* wb = W + (int64_t)1024 * 1024 + col;   // Wh starts at row 1024
        #pragma unroll
        for (int kb = 0; kb < 32; ++kb) {
            const float* src = wb + (int64_t)(kb * 32 + hi * 8) * 1024;
            bf16x8 tf;
            #pragma unroll
            for (int j = 0; j < 8; ++j) tf[j] = (__bf16)src[(int64_t)j * 1024];
            breg[kb] = tf;
        }
    }

    // staging role: 16 rows x 32 threads/row; thread (srow, c32) owns window kb=c32
    const int srow = tid >> 5;       // 0..15
    const int c32  = tid & 31;       // 0..31 == kb staged by this thread
    const int slab_u64 = (ig * 16 + srow) * 512 + c32 * 16;
    const unsigned wswz = (unsigned)(c32 & 7);

    const int64_t rstride = (int64_t)T_LEN * HID;
    float* pr0 = out + (int64_t)(ig * 16 + hi * 4) * rstride + col;
    const int wr0 = (ig * 16 + hi * 4) * 1024 + col;

    float heat = 1.0f;

    for (int t = 0; t < T_LEN; ++t) {
        // XP prefetch (overlaps the tag spin)
        float xpv0 = pr0[(int64_t)t * HID];
        float xpv1 = pr0[(int64_t)t * HID + rstride];
        float xpv2 = pr0[(int64_t)t * HID + 2 * rstride];
        float xpv3 = pr0[(int64_t)t * HID + 3 * rstride];

        f32x4 accs = {0.f, 0.f, 0.f, 0.f};
        if (t > 0) {
            const unsigned exptag = (unsigned)t;
            const u64* bp = (const u64*)(hx + ((t - 1) & 1) * 65536) + slab_u64;
            u64 q[16];
            for (;;) {
                #pragma unroll
                for (int j = 0; j < 16; ++j)
                    q[j] = __hip_atomic_load(bp + j, __ATOMIC_RELAXED, __HIP_MEMORY_SCOPE_AGENT);
                unsigned badm = 0;
                #pragma unroll
                for (int j = 0; j < 16; ++j) {
                    badm |= ((unsigned)(q[j] >> 16) & 0xffffu) ^ exptag;
                    badm |= ((unsigned)(q[j] >> 48)) ^ exptag;
                }
                if (badm == 0) break;
                // heater instead of s_sleep: keeps clocks up, spaces retries
                #pragma unroll
                for (int hh = 0; hh < 24; ++hh)
                    heat = __builtin_fmaf(heat, 1.0000001f, 1.0e-7f);
                asm volatile("" :: "v"(heat));
            }

            // unpack {tag|bf16}x2 -> packed bf16x2 dwords; conflict-free LDS write
            unsigned dwp[16];
            #pragma unroll
            for (int j = 0; j < 16; ++j)
                dwp[j] = __builtin_amdgcn_perm((unsigned)(q[j] >> 32), (unsigned)q[j], 0x05040100u);
            unsigned char* wbase = A_lds + c32 * 1024;
            #pragma unroll
            for (int i = 0; i < 4; ++i) {
                f32x4 v = { FB(dwp[4 * i]), FB(dwp[4 * i + 1]),
                            FB(dwp[4 * i + 2]), FB(dwp[4 * i + 3]) };
                *(f32x4*)(wbase + ((((unsigned)(i * 16 + srow)) ^ wswz) << 4)) = v;
            }
            __syncthreads();   // A slab staged

            // full-K MFMA vs register Wh; conflict-free reads; 4 accumulators
            f32x4 a0 = {0.f,0.f,0.f,0.f}, a1 = a0, a2 = a0, a3 = a0;
            #pragma unroll
            for (int kb = 0; kb < 32; kb += 4) {
                bf16x8 x0 = *(const bf16x8*)(A_lds + (kb + 0) * 1024 + (((unsigned)lane ^ (unsigned)((kb + 0) & 7)) << 4));
                bf16x8 x1 = *(const bf16x8*)(A_lds + (kb + 1) * 1024 + (((unsigned)lane ^ (unsigned)((kb + 1) & 7)) << 4));
                bf16x8 x2 = *(const bf16x8*)(A_lds + (kb + 2) * 1024 + (((unsigned)lane ^ (unsigned)((kb + 2) & 7)) << 4));
                bf16x8 x3 = *(const bf16x8*)(A_lds + (kb + 3) * 1024 + (((unsigned)lane ^ (unsigned)((kb + 3) & 7)) << 4));
                a0 = __builtin_amdgcn_mfma_f32_16x16x32_bf16(x0, breg[kb + 0], a0, 0, 0, 0);
                a1 = __builtin_amdgcn_mfma_f32_16x16x32_bf16(x1, breg[kb + 1], a1, 0, 0, 0);
                a2 = __builtin_amdgcn_mfma_f32_16x16x32_bf16(x2, breg[kb + 2], a2, 0, 0, 0);
                a3 = __builtin_amdgcn_mfma_f32_16x16x32_bf16(x3, breg[kb + 3], a3, 0, 0, 0);
            }
            accs = (a0 + a1) + (a2 + a3);
        }

        float h0 = tanh_fast(xpv0 + accs[0]);
        float h1 = tanh_fast(xpv1 + accs[1]);
        float h2 = tanh_fast(xpv2 + accs[2]);
        float h3 = tanh_fast(xpv3 + accs[3]);

        // exchange stores FIRST (fire-and-forget): {tag=t+1 | bf16(h)}
        const unsigned tagw = (unsigned)(t + 1) << 16;
        unsigned* q_ = hx + (t & 1) * 65536 + wr0;
        __hip_atomic_store(q_,        tagw | __builtin_bit_cast(unsigned short, (__bf16)h0), __ATOMIC_RELAXED, __HIP_MEMORY_SCOPE_AGENT);
        __hip_atomic_store(q_ + 1024, tagw | __builtin_bit_cast(unsigned short, (__bf16)h1), __ATOMIC_RELAXED, __HIP_MEMORY_SCOPE_AGENT);
        __hip_atomic_store(q_ + 2048, tagw | __builtin_bit_cast(unsigned short, (__bf16)h2), __ATOMIC_RELAXED, __HIP_MEMORY_SCOPE_AGENT);
        __hip_atomic_store(q_ + 3072, tagw | __builtin_bit_cast(unsigned short, (__bf16)h3), __ATOMIC_RELAXED, __HIP_MEMORY_SCOPE_AGENT);

        pr0[(int64_t)t * HID]               = h0;   // fp32 outputs (cached)
        pr0[(int64_t)t * HID + rstride]     = h1;
        pr0[(int64_t)t * HID + 2 * rstride] = h2;
        pr0[(int64_t)t * HID + 3 * rstride] = h3;

        __syncthreads();   // A_lds reuse guard (this step's reads vs next stage)
    }

    asm volatile("s_waitcnt vmcnt(0)" ::: "memory");
    __syncthreads();
    if (tid == 0)
        __hip_atomic_fetch_add(done, 1, __ATOMIC_RELAXED, __HIP_MEMORY_SCOPE_AGENT);
}

extern "C" void kernel_launch(void* const* d_in, const int* in_sizes, int n_in,
                              void* d_out, int out_size, void* d_ws, size_t ws_size,
                              hipStream_t stream)
{
    const float* x    = (const float*)d_in[0];   // [64,1024,1024]
    const float* W    = (const float*)d_in[1];   // [2048,1024]
    const float* bias = (const float*)d_in[2];   // [1024]
    float* out = (float*)d_out;                  // [64,1024,1024]

    unsigned int* hx   = (unsigned int*)d_ws;                 // 2 slots x 64x1024 u32 = 512 KB
    int*          done = (int*)((char*)d_ws + 524288);        // scan-completion counter

    (void)hipMemsetAsync(d_ws, 0, 524288 + 64, stream);       // zero tags + done
    xproj_gemm<<<dim3(4096), dim3(256), 0, stream>>>(x, W, bias, out);
    rnn_scan<<<dim3(256), dim3(512), 0, stream>>>(W, out, hx, done);
}